// Round 1
// baseline (492.203 us; speedup 1.0000x reference)
//
#include <hip/hip_runtime.h>

// COEFFS[program_id] = {c_h1, c_h2, c_r1, c_r2}
__device__ __constant__ float COEFFS[9][4] = {
    { 1.f,  0.f,  0.f,  0.f},
    { 0.f,  0.f,  1.f,  0.f},
    { 1.f,  0.f,  1.f,  0.f},
    { 1.f,  1.f,  0.f,  0.f},
    { 0.f,  0.f,  1.f,  1.f},
    { 1.f, -1.f,  0.f,  0.f},
    { 1.f,  0.f, -1.f,  0.f},
    {-1.f,  0.f,  1.f,  0.f},
    { 0.f,  0.f,  1.f, -1.f},
};

// One block per (b,t) image: program_id (and thus the coefficient-nonzero
// pattern) is uniform across the block, so the "skip this plane" branches are
// wave-uniform s_cbranch's — skipped planes are never fetched from HBM.
// Image = 64*64 = 4096 floats = 1024 float4; 256 threads x 4 float4 each.
__global__ __launch_bounds__(256) void gen_obs_kernel(
    const int*    __restrict__ pid,
    const float4* __restrict__ hearts,   // (8192, 2, 1024) in float4 units
    const float4* __restrict__ rects,    // (8192, 2, 1024)
    float4*       __restrict__ out)      // (8192, 1024)
{
    const int bt = blockIdx.x;           // 0..8191
    const int p  = pid[bt];
    const float c0 = COEFFS[p][0];
    const float c1 = COEFFS[p][1];
    const float c2 = COEFFS[p][2];
    const float c3 = COEFFS[p][3];

    const long long in_base  = (long long)bt * 2048;  // 2 planes * 1024 float4
    const long long out_base = (long long)bt * 1024;

    #pragma unroll
    for (int k = 0; k < 4; ++k) {
        const int pix = threadIdx.x + k * 256;        // 0..1023
        float ax = 0.f, ay = 0.f, az = 0.f, aw = 0.f;

        if (c0 != 0.f) {
            float4 v = hearts[in_base + pix];
            ax += c0 * v.x; ay += c0 * v.y; az += c0 * v.z; aw += c0 * v.w;
        }
        if (c1 != 0.f) {
            float4 v = hearts[in_base + 1024 + pix];
            ax += c1 * v.x; ay += c1 * v.y; az += c1 * v.z; aw += c1 * v.w;
        }
        if (c2 != 0.f) {
            float4 v = rects[in_base + pix];
            ax += c2 * v.x; ay += c2 * v.y; az += c2 * v.z; aw += c2 * v.w;
        }
        if (c3 != 0.f) {
            float4 v = rects[in_base + 1024 + pix];
            ax += c3 * v.x; ay += c3 * v.y; az += c3 * v.z; aw += c3 * v.w;
        }

        float4 o;
        o.x = fminf(fmaxf(ax, 0.f), 1.f);
        o.y = fminf(fmaxf(ay, 0.f), 1.f);
        o.z = fminf(fmaxf(az, 0.f), 1.f);
        o.w = fminf(fmaxf(aw, 0.f), 1.f);
        out[out_base + pix] = o;
    }
}

extern "C" void kernel_launch(void* const* d_in, const int* in_sizes, int n_in,
                              void* d_out, int out_size, void* d_ws, size_t ws_size,
                              hipStream_t stream) {
    const int*    pid    = (const int*)d_in[0];
    const float4* hearts = (const float4*)d_in[1];
    const float4* rects  = (const float4*)d_in[2];
    float4*       out    = (float4*)d_out;

    const int n_bt = in_sizes[0];   // 128*64 = 8192
    gen_obs_kernel<<<n_bt, 256, 0, stream>>>(pid, hearts, rects, out);
}